// Round 1
// baseline (955.070 us; speedup 1.0000x reference)
//
#include <hip/hip_runtime.h>

// GCN layer on MI355X:
//   node_h = segment_mean(edge_feats, dst)          [N,48]
//   h2     = segment_sum(node_h[src], dst)          [N,48]
//   edge_h = 0.5*(h2[src]+h2[dst])                  [E,48]
//   out    = edge_h @ W^T + b                       [E,48]
// E=1.6M, N=50000, F=48. Atomic-scatter pipeline; node arrays (9.6MB) are
// L2/L3-resident so atomics and gathers should be cache-absorbed.

constexpr int NN = 50000;
constexpr int F  = 48;

// one thread per edge: degree count
__global__ void k_deg(const int* __restrict__ dst, float* __restrict__ deg, int E) {
    int e = blockIdx.x * blockDim.x + threadIdx.x;
    if (e < E) atomicAdd(&deg[dst[e]], 1.0f);
}

// one thread per (edge, feature): nsum[dst[e]][f] += ef[e][f]
// flat idx -> consecutive lanes share an edge row (coalesced ef read,
// 192B-granular atomic bursts)
__global__ void k_scatter_ef(const float* __restrict__ ef, const int* __restrict__ dst,
                             float* __restrict__ nsum, int total) {
    int idx = blockIdx.x * blockDim.x + threadIdx.x;
    if (idx >= total) return;
    int e = idx / F;
    int f = idx - e * F;
    atomicAdd(&nsum[dst[e] * F + f], ef[idx]);
}

// node_h = nsum / max(deg,1), in place over nsum
__global__ void k_node_div(float* __restrict__ nsum, const float* __restrict__ deg, int total) {
    int i = blockIdx.x * blockDim.x + threadIdx.x;
    if (i >= total) return;
    float d = deg[i / F];
    nsum[i] = nsum[i] / fmaxf(d, 1.0f);
}

// one thread per (edge, feature): h2[dst[e]][f] += node_h[src[e]][f]
__global__ void k_scatter_h2(const float* __restrict__ nh, const int* __restrict__ src,
                             const int* __restrict__ dst, float* __restrict__ h2, int total) {
    int idx = blockIdx.x * blockDim.x + threadIdx.x;
    if (idx >= total) return;
    int e = idx / F;
    int f = idx - e * F;
    atomicAdd(&h2[dst[e] * F + f], nh[src[e] * F + f]);
}

// one thread per edge: eh = 0.5*(h2[src]+h2[dst]); out = eh @ W^T + b
// W/b indices are wave-uniform -> scalar (s_load) path, FMAs take SGPR operand.
__global__ __launch_bounds__(256) void k_edge_out(
    const int* __restrict__ src, const int* __restrict__ dst,
    const float* __restrict__ h2, const float* __restrict__ W,
    const float* __restrict__ b, float* __restrict__ out, int E)
{
    int e = blockIdx.x * blockDim.x + threadIdx.x;
    if (e >= E) return;
    const float4* hs = (const float4*)(h2 + (long long)src[e] * F);
    const float4* hd = (const float4*)(h2 + (long long)dst[e] * F);
    float eh[F];
#pragma unroll
    for (int i = 0; i < F / 4; i++) {
        float4 a = hs[i], c = hd[i];
        eh[4 * i + 0] = 0.5f * (a.x + c.x);
        eh[4 * i + 1] = 0.5f * (a.y + c.y);
        eh[4 * i + 2] = 0.5f * (a.z + c.z);
        eh[4 * i + 3] = 0.5f * (a.w + c.w);
    }
    float4* o4 = (float4*)(out + (long long)e * F);
    for (int o = 0; o < F; o += 4) {
        float4 acc = make_float4(b[o], b[o + 1], b[o + 2], b[o + 3]);
#pragma unroll
        for (int i = 0; i < F; i++) {
            acc.x += eh[i] * W[(o + 0) * F + i];
            acc.y += eh[i] * W[(o + 1) * F + i];
            acc.z += eh[i] * W[(o + 2) * F + i];
            acc.w += eh[i] * W[(o + 3) * F + i];
        }
        o4[o / 4] = acc;
    }
}

extern "C" void kernel_launch(void* const* d_in, const int* in_sizes, int n_in,
                              void* d_out, int out_size, void* d_ws, size_t ws_size,
                              hipStream_t stream) {
    const float* ef  = (const float*)d_in[0];
    const int*   src = (const int*)d_in[1];
    const int*   dst = (const int*)d_in[2];
    const float* W   = (const float*)d_in[3];
    const float* b   = (const float*)d_in[4];
    float* out = (float*)d_out;
    const int E = in_sizes[1];

    // workspace layout: nsum/node_h [NN*F] | h2 [NN*F] | deg [NN]
    float* nsum = (float*)d_ws;
    float* h2   = nsum + NN * F;
    float* deg  = h2 + NN * F;
    size_t zero_bytes = (size_t)(2 * NN * F + NN) * sizeof(float);
    hipMemsetAsync(d_ws, 0, zero_bytes, stream);

    const int totEF = E * F;          // 76.8M, fits int32
    const int totNF = NN * F;

    k_deg<<<(E + 255) / 256, 256, 0, stream>>>(dst, deg, E);
    k_scatter_ef<<<(totEF + 255) / 256, 256, 0, stream>>>(ef, dst, nsum, totEF);
    k_node_div<<<(totNF + 255) / 256, 256, 0, stream>>>(nsum, deg, totNF);
    k_scatter_h2<<<(totEF + 255) / 256, 256, 0, stream>>>(nsum, src, dst, h2, totEF);
    k_edge_out<<<(E + 255) / 256, 256, 0, stream>>>(src, dst, h2, W, b, out, E);
}